// Round 1
// baseline (178.739 us; speedup 1.0000x reference)
//
#include <hip/hip_runtime.h>
#include <math.h>

#define BIMG 32
#define QN 900
#define CN 80
#define NCAND (QN * CN)      // 72000
#define MAXDET 100
#define LISTCAP 2048
#define TSEL 1024u
#define NTHREADS 1024

__device__ __forceinline__ uint32_t fkey(float f) {
    uint32_t u = __float_as_uint(f);
    return (u & 0x80000000u) ? ~u : (u | 0x80000000u);
}
__device__ __forceinline__ float fkey_inv(uint32_t k) {
    uint32_t u = (k & 0x80000000u) ? (k ^ 0x80000000u) : ~k;
    return __uint_as_float(u);
}

__global__ __launch_bounds__(NTHREADS)
void ov_postprocess_kernel(const float* __restrict__ logits,
                           const float* __restrict__ boxes,
                           const int* __restrict__ tsizes,
                           float* __restrict__ out)
{
    __shared__ float s_xyxy[QN][4];          // 14400 B
    __shared__ uint32_t s_finq[QN];          // 3600 B
    __shared__ unsigned long long s_list[LISTCAP]; // 16384 B
    __shared__ uint32_t s_hist[256];         // 1024 B
    __shared__ float s_red[NTHREADS];        // 4096 B
    __shared__ float s_accbox[MAXDET][4];    // 1600 B
    __shared__ float s_accarea[MAXDET];
    __shared__ int   s_accq[MAXDET];
    __shared__ int   s_accc[MAXDET];
    __shared__ float s_accsc[MAXDET];
    __shared__ uint32_t s_cnt;
    __shared__ uint32_t s_kthr;
    __shared__ uint32_t s_b1;
    __shared__ uint32_t s_cabove;
    __shared__ float s_off;
    __shared__ int s_nacc;

    const int b = blockIdx.x;
    const int tid = threadIdx.x;
    const float* lg = logits + (size_t)b * NCAND;
    const float* bxp = boxes + (size_t)b * QN * 4;

    if (tid == 0) { s_cnt = 0u; s_kthr = 0u; s_b1 = 0xFFFFFFFFu; s_cabove = 0u; }

    // ---- Phase A: cxcywh -> xyxy, per-query box finiteness ----
    for (int q = tid; q < QN; q += NTHREADS) {
        float cx = bxp[q * 4 + 0], cy = bxp[q * 4 + 1];
        float w  = bxp[q * 4 + 2], h  = bxp[q * 4 + 3];
        float hw = 0.5f * w, hh = 0.5f * h;
        float x1 = cx - hw, y1 = cy - hh, x2 = cx + hw, y2 = cy + hh;
        s_xyxy[q][0] = x1; s_xyxy[q][1] = y1; s_xyxy[q][2] = x2; s_xyxy[q][3] = y2;
        uint32_t fin = (isfinite(x1) && isfinite(y1) && isfinite(x2) && isfinite(y2)) ? 1u : 0u;
        s_finq[q] = fin;
    }
    __syncthreads();

    // ---- logits finiteness (invalidate whole query on any non-finite logit) ----
    for (int i = tid; i < NCAND; i += NTHREADS) {
        float L = lg[i];
        if (!isfinite(L)) s_finq[i / CN] = 0u;
    }

    // ---- off = max(where(isfinite(xyxy), xyxy, 0)) + 1 ----
    float m = -INFINITY;
    for (int q = tid; q < QN; q += NTHREADS) {
        #pragma unroll
        for (int k = 0; k < 4; ++k) {
            float v = s_xyxy[q][k];
            m = fmaxf(m, isfinite(v) ? v : 0.0f);
        }
    }
    s_red[tid] = m;
    __syncthreads();
    for (int s = NTHREADS / 2; s > 0; s >>= 1) {
        if (tid < s) s_red[tid] = fmaxf(s_red[tid], s_red[tid + s]);
        __syncthreads();
    }
    if (tid == 0) s_off = s_red[0] + 1.0f;

    // ---- Round 1 histogram over key[31:24] of valid candidates ----
    if (tid < 256) s_hist[tid] = 0u;
    __syncthreads();
    for (int i = tid; i < NCAND; i += NTHREADS) {
        float L = lg[i];
        if (!s_finq[i / CN]) continue;
        float sc = 1.0f / (1.0f + expf(-L));
        if (!(sc > 1e-3f)) continue;
        atomicAdd(&s_hist[fkey(L) >> 24], 1u);
    }
    __syncthreads();
    if (tid == 0) {
        uint32_t cum = 0; int b1 = -1; uint32_t cab = 0;
        for (int v = 255; v >= 0; --v) {
            if (cum + s_hist[v] >= TSEL) { b1 = v; cab = cum; break; }
            cum += s_hist[v];
        }
        if (b1 < 0) { s_kthr = 0u; s_b1 = 0xFFFFFFFFu; }   // fewer than TSEL valid -> take all
        else { s_b1 = (uint32_t)b1; s_cabove = cab; }
    }
    __syncthreads();

    // ---- Round 2 histogram over key[23:16] within boundary bin ----
    uint32_t b1v = s_b1;
    if (b1v != 0xFFFFFFFFu) {
        if (tid < 256) s_hist[tid] = 0u;
        __syncthreads();
        for (int i = tid; i < NCAND; i += NTHREADS) {
            float L = lg[i];
            if (!s_finq[i / CN]) continue;
            float sc = 1.0f / (1.0f + expf(-L));
            if (!(sc > 1e-3f)) continue;
            uint32_t k = fkey(L);
            if ((k >> 24) == b1v) atomicAdd(&s_hist[(k >> 16) & 0xFFu], 1u);
        }
        __syncthreads();
        if (tid == 0) {
            uint32_t cum = s_cabove; uint32_t b2 = 0;
            for (int v = 255; v >= 0; --v) {
                if (cum + s_hist[v] >= TSEL) { b2 = (uint32_t)v; break; }
                cum += s_hist[v];
            }
            s_kthr = (b1v << 24) | (b2 << 16);
        }
    }
    __syncthreads();

    // ---- Compaction ----
    uint32_t kthr = s_kthr;
    for (int i = tid; i < NCAND; i += NTHREADS) {
        float L = lg[i];
        if (!s_finq[i / CN]) continue;
        float sc = 1.0f / (1.0f + expf(-L));
        if (!(sc > 1e-3f)) continue;
        uint32_t k = fkey(L);
        if (k >= kthr) {
            uint32_t pos = atomicAdd(&s_cnt, 1u);
            if (pos < LISTCAP)
                s_list[pos] = ((unsigned long long)k << 32) | (unsigned long long)(~(uint32_t)i);
        }
    }
    __syncthreads();
    uint32_t nlist = s_cnt; if (nlist > LISTCAP) nlist = LISTCAP;
    for (uint32_t i = nlist + tid; i < LISTCAP; i += NTHREADS) s_list[i] = 0ull;

    // ---- Bitonic sort descending (2048 elems, 1024 threads) ----
    for (uint32_t k = 2; k <= LISTCAP; k <<= 1) {
        for (uint32_t j = k >> 1; j > 0; j >>= 1) {
            __syncthreads();
            for (uint32_t t = tid; t < LISTCAP; t += NTHREADS) {
                uint32_t ixj = t ^ j;
                if (ixj > t) {
                    unsigned long long a = s_list[t], c = s_list[ixj];
                    bool doswap = ((t & k) == 0) ? (a < c) : (a > c);
                    if (doswap) { s_list[t] = c; s_list[ixj] = a; }
                }
            }
        }
    }
    __syncthreads();

    // ---- Greedy NMS on sorted list (wave 0 only) ----
    if (tid < 64) {
        int nacc = 0;
        float off = s_off;
        for (uint32_t e = 0; e < nlist && nacc < MAXDET; ++e) {
            unsigned long long pk = s_list[e];
            uint32_t key = (uint32_t)(pk >> 32);
            uint32_t idx = ~((uint32_t)pk);
            int q = (int)(idx / CN), c = (int)(idx % CN);
            float ofc = (float)c * off;
            float x1 = s_xyxy[q][0] + ofc;
            float y1 = s_xyxy[q][1] + ofc;
            float x2 = s_xyxy[q][2] + ofc;
            float y2 = s_xyxy[q][3] + ofc;
            float carea = fmaxf(x2 - x1, 0.0f) * fmaxf(y2 - y1, 0.0f);
            bool sup = false;
            for (int a = tid; a < nacc; a += 64) {
                float ax1 = s_accbox[a][0], ay1 = s_accbox[a][1];
                float ax2 = s_accbox[a][2], ay2 = s_accbox[a][3];
                float ltx = fmaxf(ax1, x1), lty = fmaxf(ay1, y1);
                float rbx = fminf(ax2, x2), rby = fminf(ay2, y2);
                float iw = fmaxf(rbx - ltx, 0.0f), ih = fmaxf(rby - lty, 0.0f);
                float inter = iw * ih;
                // union = area(selected) + area(candidate) - inter  (ref order)
                float uni = s_accarea[a] + carea - inter;
                float iou = inter / fmaxf(uni, 1e-9f);
                sup = sup || (iou > 0.5f);
            }
            if (__any((int)sup)) continue;
            if (tid == 0) {
                s_accbox[nacc][0] = x1; s_accbox[nacc][1] = y1;
                s_accbox[nacc][2] = x2; s_accbox[nacc][3] = y2;
                s_accarea[nacc] = carea;
                s_accq[nacc] = q;
                s_accc[nacc] = c;
                float L = fkey_inv(key);
                s_accsc[nacc] = 1.0f / (1.0f + expf(-L));
            }
            __threadfence_block();
            nacc++;
        }
        if (tid == 0) s_nacc = nacc;
    }
    __syncthreads();

    // ---- Outputs: [scs 32x100][lab 32x100][boxes 32x100x4][goods 32x100], all f32 ----
    if (tid < MAXDET) {
        const int* ts = tsizes + b * 2;
        float th = (float)ts[0], tw = (float)ts[1];   // (h, w)
        int d = tid;
        bool good = d < s_nacc;
        float sc = good ? s_accsc[d] : 0.0f;
        float lb = good ? (float)s_accc[d] : -1.0f;
        float gd = good ? 1.0f : 0.0f;
        float bx1 = 0.0f, by1 = 0.0f, bx2 = 0.0f, by2 = 0.0f;
        if (good) {
            int q = s_accq[d];
            bx1 = s_xyxy[q][0] * tw;
            by1 = s_xyxy[q][1] * th;
            bx2 = s_xyxy[q][2] * tw;
            by2 = s_xyxy[q][3] * th;
        }
        float* out_scs  = out;
        float* out_lab  = out + BIMG * MAXDET;
        float* out_box  = out + 2 * BIMG * MAXDET;
        float* out_good = out + 2 * BIMG * MAXDET + BIMG * MAXDET * 4;
        out_scs[b * MAXDET + d] = sc;
        out_lab[b * MAXDET + d] = lb;
        float* ob = out_box + (size_t)(b * MAXDET + d) * 4;
        ob[0] = bx1; ob[1] = by1; ob[2] = bx2; ob[3] = by2;
        out_good[b * MAXDET + d] = gd;
    }
}

extern "C" void kernel_launch(void* const* d_in, const int* in_sizes, int n_in,
                              void* d_out, int out_size, void* d_ws, size_t ws_size,
                              hipStream_t stream) {
    const float* pred_logits = (const float*)d_in[0];
    const float* pred_boxes  = (const float*)d_in[1];
    const int*   target_sizes = (const int*)d_in[2];
    float* out = (float*)d_out;
    ov_postprocess_kernel<<<BIMG, NTHREADS, 0, stream>>>(pred_logits, pred_boxes, target_sizes, out);
}